// Round 1
// baseline (18546.802 us; speedup 1.0000x reference)
//
#include <hip/hip_runtime.h>
#include <hip/hip_bf16.h>

// Problem constants
#define TB_ 1024          // T
#define BB_ 2             // B
#define MM_ 2048          // B*T rows
#define CC_ 1024          // C
#define HH_ 16            // heads
#define DD_ 64            // head dim
#define LL_ 8             // layers
#define HID_ 4096
#define VV_ 32000

__device__ __forceinline__ float gelu_f(float x) {
    // exact gelu: 0.5*x*(1+erf(x/sqrt(2)))
    return 0.5f * x * (1.0f + erff(x * 0.70710678118654752f));
}

// -------------------- embedding: x = tok_emb[idx] + pos_emb --------------------
__global__ __launch_bounds__(256) void embed_kernel(
    const int* __restrict__ idx, const float4* __restrict__ tok,
    const float4* __restrict__ pos, float4* __restrict__ x) {
    int row = blockIdx.x;          // 0..2047 (b*T + t)
    int t   = row & (TB_ - 1);
    int tid = threadIdx.x;         // 256 threads, 1 float4 each (C/4 = 256)
    int id  = idx[row];
    float4 a = tok[(size_t)id * 256 + tid];
    float4 p = pos[(size_t)t  * 256 + tid];
    float4 r; r.x = a.x + p.x; r.y = a.y + p.y; r.z = a.z + p.z; r.w = a.w + p.w;
    x[(size_t)row * 256 + tid] = r;
}

// -------------------- layernorm over C=1024, one block per row --------------------
__global__ __launch_bounds__(256) void ln_kernel(
    const float* __restrict__ x, const float* __restrict__ g,
    const float* __restrict__ bb, float* __restrict__ o) {
    int row = blockIdx.x;
    int tid = threadIdx.x;
    const float* xr = x + (size_t)row * CC_;
    float v[4];
    float s = 0.f;
    #pragma unroll
    for (int i = 0; i < 4; ++i) { v[i] = xr[tid + 256 * i]; s += v[i]; }
    #pragma unroll
    for (int off = 32; off > 0; off >>= 1) s += __shfl_xor(s, off);
    __shared__ float r1[4], r2[4];
    int wid = tid >> 6;
    if ((tid & 63) == 0) r1[wid] = s;
    __syncthreads();
    float mean = (r1[0] + r1[1] + r1[2] + r1[3]) * (1.f / CC_);
    float s2 = 0.f;
    #pragma unroll
    for (int i = 0; i < 4; ++i) { float d = v[i] - mean; s2 += d * d; }
    #pragma unroll
    for (int off = 32; off > 0; off >>= 1) s2 += __shfl_xor(s2, off);
    if ((tid & 63) == 0) r2[wid] = s2;
    __syncthreads();
    float var  = (r2[0] + r2[1] + r2[2] + r2[3]) * (1.f / CC_);
    float rstd = rsqrtf(var + 1e-5f);
    #pragma unroll
    for (int i = 0; i < 4; ++i) {
        int c = tid + 256 * i;
        o[(size_t)row * CC_ + c] = (v[i] - mean) * rstd * g[c] + bb[c];
    }
}

// -------------------- generic tiled GEMM: C = A[M,K] @ B (+bias, gelu, +res) ----
// TB=false: B is [K,N] row-major.  TB=true: B is [N,K] row-major (B transposed).
// All of M,N multiples of 64; K multiple of 16 (true for every call here).
template <bool TB, bool GELU>
__global__ __launch_bounds__(256) void gemm_kernel(
    const float* __restrict__ A, const float* __restrict__ B,
    const float* __restrict__ bias, const float* __restrict__ res,
    float* __restrict__ C, int M, int N, int K) {
    __shared__ float As[64][17];
    __shared__ float Bs[16][65];
    int tid = threadIdx.x;
    int tx = tid & 15, ty = tid >> 4;
    int row0 = blockIdx.y * 64, col0 = blockIdx.x * 64;
    float acc[4][4] = {{0.f}};
    for (int k0 = 0; k0 < K; k0 += 16) {
        {   // A tile 64x16
            int r = tid >> 4, c = tid & 15;
            #pragma unroll
            for (int p = 0; p < 4; ++p)
                As[p * 16 + r][c] = A[(size_t)(row0 + p * 16 + r) * K + k0 + c];
        }
        if (!TB) {  // B tile 16x64 from [K,N]
            int r = tid >> 6, c = tid & 63;
            #pragma unroll
            for (int p = 0; p < 4; ++p)
                Bs[p * 4 + r][c] = B[(size_t)(k0 + p * 4 + r) * N + col0 + c];
        } else {    // B tile from [N,K]
            int kq = tid & 15, n = tid >> 4;
            #pragma unroll
            for (int p = 0; p < 4; ++p)
                Bs[kq][p * 16 + n] = B[(size_t)(col0 + p * 16 + n) * K + k0 + kq];
        }
        __syncthreads();
        #pragma unroll
        for (int kk = 0; kk < 16; ++kk) {
            float a[4], b[4];
            #pragma unroll
            for (int i = 0; i < 4; ++i) a[i] = As[ty * 4 + i][kk];
            #pragma unroll
            for (int j = 0; j < 4; ++j) b[j] = Bs[kk][tx * 4 + j];
            #pragma unroll
            for (int i = 0; i < 4; ++i)
                #pragma unroll
                for (int j = 0; j < 4; ++j)
                    acc[i][j] += a[i] * b[j];
        }
        __syncthreads();
    }
    #pragma unroll
    for (int i = 0; i < 4; ++i) {
        int r = row0 + ty * 4 + i;
        #pragma unroll
        for (int j = 0; j < 4; ++j) {
            int c = col0 + tx * 4 + j;
            float v2 = acc[i][j];
            if (bias) v2 += bias[c];
            if (GELU) v2 = gelu_f(v2);
            if (res)  v2 += res[(size_t)r * N + c];
            C[(size_t)r * N + c] = v2;
        }
    }
}

// -------------------- causal attention, one wave per (b, h, t_q) row ------------
// qkv layout: [B*T, 3C] with q at col h*64, k at C + h*64, v at 2C + h*64.
// att layout: [B*T, C] with head h at col h*64 (already [B,T,H,D] merged).
__global__ __launch_bounds__(64) void attn_kernel(
    const float* __restrict__ qkv, float* __restrict__ att) {
    __shared__ float sc[TB_];
    __shared__ float sq[DD_];
    int tq = blockIdx.x;
    int b  = blockIdx.y >> 4, h = blockIdx.y & 15;
    int lane = threadIdx.x;
    const int C3 = 3 * CC_;
    const float* base = qkv + (size_t)b * TB_ * C3;
    sq[lane] = base[(size_t)tq * C3 + h * DD_ + lane];
    __syncthreads();
    const float* kb = base + CC_     + h * DD_;
    const float* vb = base + 2 * CC_ + h * DD_;
    // scores
    for (int j = lane; j <= tq; j += 64) {
        const float4* kr = (const float4*)(kb + (size_t)j * C3);
        float d = 0.f;
        #pragma unroll
        for (int t = 0; t < 16; ++t) {
            float4 kv = kr[t];
            d += sq[4 * t] * kv.x + sq[4 * t + 1] * kv.y +
                 sq[4 * t + 2] * kv.z + sq[4 * t + 3] * kv.w;
        }
        sc[j] = d * 0.125f;   // D^-0.5 = 1/8
    }
    __syncthreads();
    // softmax over sc[0..tq]
    float mx = -1e30f;
    for (int j = lane; j <= tq; j += 64) mx = fmaxf(mx, sc[j]);
    #pragma unroll
    for (int o = 32; o > 0; o >>= 1) mx = fmaxf(mx, __shfl_xor(mx, o));
    float sm = 0.f;
    for (int j = lane; j <= tq; j += 64) {
        float e = __expf(sc[j] - mx); sc[j] = e; sm += e;
    }
    #pragma unroll
    for (int o = 32; o > 0; o >>= 1) sm += __shfl_xor(sm, o);
    __syncthreads();
    float inv = 1.0f / sm;
    // out[d=lane] = sum_j p[j] * V[j][d]
    float a0 = 0, a1 = 0, a2 = 0, a3 = 0;
    int j = 0;
    for (; j + 4 <= tq + 1; j += 4) {
        a0 += sc[j]     * vb[(size_t)j * C3 + lane];
        a1 += sc[j + 1] * vb[(size_t)(j + 1) * C3 + lane];
        a2 += sc[j + 2] * vb[(size_t)(j + 2) * C3 + lane];
        a3 += sc[j + 3] * vb[(size_t)(j + 3) * C3 + lane];
    }
    for (; j <= tq; ++j) a0 += sc[j] * vb[(size_t)j * C3 + lane];
    att[((size_t)(b * TB_ + tq)) * CC_ + h * DD_ + lane] = (a0 + a1 + a2 + a3) * inv;
}

extern "C" void kernel_launch(void* const* d_in, const int* in_sizes, int n_in,
                              void* d_out, int out_size, void* d_ws, size_t ws_size,
                              hipStream_t stream) {
    const int*   idx     = (const int*)  d_in[0];
    const float* tok_emb = (const float*)d_in[1];
    const float* pos_emb = (const float*)d_in[2];
    const float* qkv_w   = (const float*)d_in[3];
    const float* proj_w  = (const float*)d_in[4];
    const float* proj_b  = (const float*)d_in[5];
    const float* ln1_g   = (const float*)d_in[6];
    const float* ln1_b   = (const float*)d_in[7];
    const float* ln2_g   = (const float*)d_in[8];
    const float* ln2_b   = (const float*)d_in[9];
    const float* fc1_w   = (const float*)d_in[10];
    const float* fc1_b   = (const float*)d_in[11];
    const float* fc2_w   = (const float*)d_in[12];
    const float* fc2_b   = (const float*)d_in[13];
    const float* lnf_g   = (const float*)d_in[14];
    const float* lnf_b   = (const float*)d_in[15];
    float* out = (float*)d_out;

    // workspace: x (8MB) | hb (8MB, doubles as ln-out and attention-out) |
    //            big (32MB, doubles as qkv buffer and ffn hidden)
    float* x   = (float*)d_ws;                       // 2048*1024
    float* hb  = x  + (size_t)MM_ * CC_;             // 2048*1024
    float* big = hb + (size_t)MM_ * CC_;             // 2048*4096

    embed_kernel<<<MM_, 256, 0, stream>>>(idx, (const float4*)tok_emb,
                                          (const float4*)pos_emb, (float4*)x);
    for (int l = 0; l < LL_; ++l) {
        // h = LN1(x)
        ln_kernel<<<MM_, 256, 0, stream>>>(x, ln1_g + l * CC_, ln1_b + l * CC_, hb);
        // qkv = h @ qkv_w   [2048,1024]@[1024,3072]
        gemm_kernel<false, false><<<dim3(3 * CC_ / 64, MM_ / 64), 256, 0, stream>>>(
            hb, qkv_w + (size_t)l * CC_ * 3 * CC_, nullptr, nullptr, big,
            MM_, 3 * CC_, CC_);
        // att = causal_attention(qkv)  (reuses hb)
        attn_kernel<<<dim3(TB_, BB_ * HH_), 64, 0, stream>>>(big, hb);
        // x = x + att @ proj_w + proj_b
        gemm_kernel<false, false><<<dim3(CC_ / 64, MM_ / 64), 256, 0, stream>>>(
            hb, proj_w + (size_t)l * CC_ * CC_, proj_b + l * CC_, x, x,
            MM_, CC_, CC_);
        // h = LN2(x)
        ln_kernel<<<MM_, 256, 0, stream>>>(x, ln2_g + l * CC_, ln2_b + l * CC_, hb);
        // ffh = gelu(h @ fc1_w + fc1_b)
        gemm_kernel<false, true><<<dim3(HID_ / 64, MM_ / 64), 256, 0, stream>>>(
            hb, fc1_w + (size_t)l * CC_ * HID_, fc1_b + l * HID_, nullptr, big,
            MM_, HID_, CC_);
        // x = x + ffh @ fc2_w + fc2_b
        gemm_kernel<false, false><<<dim3(CC_ / 64, MM_ / 64), 256, 0, stream>>>(
            big, fc2_w + (size_t)l * HID_ * CC_, fc2_b + l * CC_, x, x,
            MM_, CC_, HID_);
    }
    // final LN + tied lm_head: logits = LN_f(x) @ tok_emb^T
    ln_kernel<<<MM_, 256, 0, stream>>>(x, lnf_g, lnf_b, hb);
    gemm_kernel<true, false><<<dim3(VV_ / 64, MM_ / 64), 256, 0, stream>>>(
        hb, tok_emb, nullptr, nullptr, out, MM_, VV_, CC_);
}

// Round 2
// 8976.198 us; speedup vs baseline: 2.0662x; 2.0662x over previous
//
#include <hip/hip_runtime.h>
#include <hip/hip_bf16.h>

// Problem constants
#define TB_ 1024          // T
#define BB_ 2             // B
#define MM_ 2048          // B*T rows
#define CC_ 1024          // C
#define HH_ 16            // heads
#define DD_ 64            // head dim
#define LL_ 8             // layers
#define HID_ 4096
#define VV_ 32000

typedef short short8 __attribute__((ext_vector_type(8)));
typedef short short4v __attribute__((ext_vector_type(4)));
typedef float f32x4 __attribute__((ext_vector_type(4)));
typedef unsigned short ushort;

__device__ __forceinline__ float gelu_f(float x) {
    return 0.5f * x * (1.0f + erff(x * 0.70710678118654752f));
}

// fp32 -> bf16 bits, round-to-nearest-even
__device__ __forceinline__ ushort f2bf(float x) {
    union { float f; unsigned u; } v; v.f = x;
    unsigned r = v.u + 0x7FFF + ((v.u >> 16) & 1);
    return (ushort)(r >> 16);
}

// async global->LDS, 16B per lane; lds dest must be wave-uniform base (+lane*16 by HW)
__device__ __forceinline__ void load_lds16(const void* g, void* l) {
    __builtin_amdgcn_global_load_lds(
        (__attribute__((address_space(1))) void*)(uintptr_t)g,
        (__attribute__((address_space(3))) void*)(uintptr_t)l, 16, 0, 0);
}

// -------------------- embedding: x = tok_emb[idx] + pos_emb --------------------
__global__ __launch_bounds__(256) void embed_kernel(
    const int* __restrict__ idx, const float4* __restrict__ tok,
    const float4* __restrict__ pos, float4* __restrict__ x) {
    int row = blockIdx.x;
    int t   = row & (TB_ - 1);
    int tid = threadIdx.x;
    int id  = idx[row];
    float4 a = tok[(size_t)id * 256 + tid];
    float4 p = pos[(size_t)t  * 256 + tid];
    float4 r; r.x = a.x + p.x; r.y = a.y + p.y; r.z = a.z + p.z; r.w = a.w + p.w;
    x[(size_t)row * 256 + tid] = r;
}

// -------------------- layernorm over C=1024, fp32 in, bf16 out --------------------
__global__ __launch_bounds__(256) void ln_kernel(
    const float* __restrict__ x, const float* __restrict__ g,
    const float* __restrict__ bb, ushort* __restrict__ o) {
    int row = blockIdx.x;
    int tid = threadIdx.x;
    const float* xr = x + (size_t)row * CC_;
    float v[4];
    float s = 0.f;
    #pragma unroll
    for (int i = 0; i < 4; ++i) { v[i] = xr[tid + 256 * i]; s += v[i]; }
    #pragma unroll
    for (int off = 32; off > 0; off >>= 1) s += __shfl_xor(s, off);
    __shared__ float r1[4], r2[4];
    int wid = tid >> 6;
    if ((tid & 63) == 0) r1[wid] = s;
    __syncthreads();
    float mean = (r1[0] + r1[1] + r1[2] + r1[3]) * (1.f / CC_);
    float s2 = 0.f;
    #pragma unroll
    for (int i = 0; i < 4; ++i) { float d = v[i] - mean; s2 += d * d; }
    #pragma unroll
    for (int off = 32; off > 0; off >>= 1) s2 += __shfl_xor(s2, off);
    if ((tid & 63) == 0) r2[wid] = s2;
    __syncthreads();
    float var  = (r2[0] + r2[1] + r2[2] + r2[3]) * (1.f / CC_);
    float rstd = rsqrtf(var + 1e-5f);
    #pragma unroll
    for (int i = 0; i < 4; ++i) {
        int c = tid + 256 * i;
        o[(size_t)row * CC_ + c] = f2bf((v[i] - mean) * rstd * g[c] + bb[c]);
    }
}

// ------------- weight transpose+convert: fp32 [K,N] -> bf16 [N,K] -------------
__global__ __launch_bounds__(256) void convt_kernel(
    const float* __restrict__ w, ushort* __restrict__ o, int K, int N) {
    __shared__ ushort t[64][65];
    int n0 = blockIdx.x * 64, k0 = blockIdx.y * 64;
    int tid = threadIdx.x;
    #pragma unroll
    for (int i = 0; i < 4; ++i) {
        int seg = tid + i * 256;          // 1024 segs = 64 rows * 16 float4
        int r = seg >> 4, c4 = (seg & 15) * 4;
        float4 v = *(const float4*)(w + (size_t)(k0 + r) * N + n0 + c4);
        t[r][c4 + 0] = f2bf(v.x); t[r][c4 + 1] = f2bf(v.y);
        t[r][c4 + 2] = f2bf(v.z); t[r][c4 + 3] = f2bf(v.w);
    }
    __syncthreads();
    #pragma unroll
    for (int i = 0; i < 2; ++i) {
        int seg = tid + i * 256;          // 512 segs = 64 n-rows * 8 chunks
        int n = seg >> 3, k8 = (seg & 7) * 8;
        short8 p;
        #pragma unroll
        for (int j = 0; j < 8; ++j) p[j] = (short)t[k8 + j][n];
        *(short8*)(o + (size_t)(n0 + n) * K + k0 + k8) = p;
    }
}

// -------------------- MFMA GEMM: C = A[M,K](bf16) @ Bt[N,K]^T --------------------
// BSRC=0: Bt is bf16 [N,K] (global_load_lds).  BSRC=1: Bt is fp32 [N,K] (reg staging).
// grid = (M/128, N/128). 256 threads = 4 waves, each wave 64x64 (4x4 of 16x16x32).
template <int BSRC, bool BIASF, bool GELUF, bool RESF, bool OBF16>
__global__ __launch_bounds__(256) void mgemm(
    const ushort* __restrict__ A, const void* __restrict__ Bv,
    const float* __restrict__ bias, const float* __restrict__ res,
    void* __restrict__ Cp, int M, int N, int K) {
    __shared__ ushort As[128 * 32];
    __shared__ ushort Bs[128 * 32];
    int tid = threadIdx.x;
    int lane = tid & 63, wv = tid >> 6;
    int row0 = blockIdx.x * 128, col0 = blockIdx.y * 128;
    int wr = (wv >> 1) * 64, wc = (wv & 1) * 64;
    const ushort* Bb = (const ushort*)Bv;
    const float*  Bf = (const float*)Bv;
    f32x4 acc[4][4];
    #pragma unroll
    for (int i = 0; i < 4; ++i)
        #pragma unroll
        for (int j = 0; j < 4; ++j)
            acc[i][j] = (f32x4){0.f, 0.f, 0.f, 0.f};

    for (int k0 = 0; k0 < K; k0 += 32) {
        // A tile 128x32 bf16 via async direct-to-LDS (contiguous [row][k] layout)
        #pragma unroll
        for (int it = 0; it < 2; ++it) {
            int seg = it * 256 + tid;                // 512 segs of 16B
            int r = seg >> 2, c8 = (seg & 3) * 8;
            load_lds16(A + (size_t)(row0 + r) * K + k0 + c8,
                       &As[(size_t)(it * 256 + wv * 64) * 8]);
        }
        if (BSRC == 0) {
            #pragma unroll
            for (int it = 0; it < 2; ++it) {
                int seg = it * 256 + tid;
                int n = seg >> 2, c8 = (seg & 3) * 8;
                load_lds16(Bb + (size_t)(col0 + n) * K + k0 + c8,
                           &Bs[(size_t)(it * 256 + wv * 64) * 8]);
            }
        } else {
            #pragma unroll
            for (int it = 0; it < 4; ++it) {
                int seg = it * 256 + tid;            // 1024 segs of float4
                int n = seg >> 3, c4 = (seg & 7) * 4;
                float4 v = *(const float4*)(Bf + (size_t)(col0 + n) * K + k0 + c4);
                short4v p;
                p[0] = (short)f2bf(v.x); p[1] = (short)f2bf(v.y);
                p[2] = (short)f2bf(v.z); p[3] = (short)f2bf(v.w);
                *(short4v*)&Bs[n * 32 + c4] = p;
            }
        }
        __syncthreads();
        short8 af[4], bfv[4];
        #pragma unroll
        for (int i = 0; i < 4; ++i)
            af[i] = *(const short8*)&As[(wr + i * 16 + (lane & 15)) * 32 + (lane >> 4) * 8];
        #pragma unroll
        for (int j = 0; j < 4; ++j)
            bfv[j] = *(const short8*)&Bs[(wc + j * 16 + (lane & 15)) * 32 + (lane >> 4) * 8];
        #pragma unroll
        for (int i = 0; i < 4; ++i)
            #pragma unroll
            for (int j = 0; j < 4; ++j)
                acc[i][j] = __builtin_amdgcn_mfma_f32_16x16x32_bf16(
                    af[i], bfv[j], acc[i][j], 0, 0, 0);
        __syncthreads();
    }

    float* Co = (float*)Cp;
    ushort* Cb = (ushort*)Cp;
    #pragma unroll
    for (int i = 0; i < 4; ++i) {
        #pragma unroll
        for (int j = 0; j < 4; ++j) {
            #pragma unroll
            for (int r = 0; r < 4; ++r) {
                int row = row0 + wr + i * 16 + (lane >> 4) * 4 + r;
                int col = col0 + wc + j * 16 + (lane & 15);
                float v = acc[i][j][r];
                if (BIASF) v += bias[col];
                if (GELUF) v = gelu_f(v);
                if (RESF)  v += res[(size_t)row * N + col];
                if (OBF16) Cb[(size_t)row * N + col] = f2bf(v);
                else       Co[(size_t)row * N + col] = v;
            }
        }
    }
}

// -------------------- causal attention, one wave per (b, h, t_q) ----------------
// qkv fp32 [B*T, 3C]; out bf16 [B*T, C] with head h at col h*64.
__global__ __launch_bounds__(64) void attn_kernel(
    const float* __restrict__ qkv, ushort* __restrict__ att) {
    __shared__ float sc[TB_];
    __shared__ float sq[DD_];
    int tq = blockIdx.x;
    int b  = blockIdx.y >> 4, h = blockIdx.y & 15;
    int lane = threadIdx.x;
    const int C3 = 3 * CC_;
    const float* base = qkv + (size_t)b * TB_ * C3;
    sq[lane] = base[(size_t)tq * C3 + h * DD_ + lane];
    __syncthreads();
    const float* kb = base + CC_     + h * DD_;
    const float* vb = base + 2 * CC_ + h * DD_;
    for (int j = lane; j <= tq; j += 64) {
        const float4* kr = (const float4*)(kb + (size_t)j * C3);
        float d = 0.f;
        #pragma unroll
        for (int t = 0; t < 16; ++t) {
            float4 kv = kr[t];
            d += sq[4 * t] * kv.x + sq[4 * t + 1] * kv.y +
                 sq[4 * t + 2] * kv.z + sq[4 * t + 3] * kv.w;
        }
        sc[j] = d * 0.125f;
    }
    __syncthreads();
    float mx = -1e30f;
    for (int j = lane; j <= tq; j += 64) mx = fmaxf(mx, sc[j]);
    #pragma unroll
    for (int o = 32; o > 0; o >>= 1) mx = fmaxf(mx, __shfl_xor(mx, o));
    float sm = 0.f;
    for (int j = lane; j <= tq; j += 64) {
        float e = __expf(sc[j] - mx); sc[j] = e; sm += e;
    }
    #pragma unroll
    for (int o = 32; o > 0; o >>= 1) sm += __shfl_xor(sm, o);
    __syncthreads();
    float inv = 1.0f / sm;
    float a0 = 0, a1 = 0, a2 = 0, a3 = 0;
    int j = 0;
    for (; j + 4 <= tq + 1; j += 4) {
        a0 += sc[j]     * vb[(size_t)j * C3 + lane];
        a1 += sc[j + 1] * vb[(size_t)(j + 1) * C3 + lane];
        a2 += sc[j + 2] * vb[(size_t)(j + 2) * C3 + lane];
        a3 += sc[j + 3] * vb[(size_t)(j + 3) * C3 + lane];
    }
    for (; j <= tq; ++j) a0 += sc[j] * vb[(size_t)j * C3 + lane];
    att[((size_t)(b * TB_ + tq)) * CC_ + h * DD_ + lane] =
        f2bf((a0 + a1 + a2 + a3) * inv);
}

extern "C" void kernel_launch(void* const* d_in, const int* in_sizes, int n_in,
                              void* d_out, int out_size, void* d_ws, size_t ws_size,
                              hipStream_t stream) {
    const int*   idx     = (const int*)  d_in[0];
    const float* tok_emb = (const float*)d_in[1];
    const float* pos_emb = (const float*)d_in[2];
    const float* qkv_w   = (const float*)d_in[3];
    const float* proj_w  = (const float*)d_in[4];
    const float* proj_b  = (const float*)d_in[5];
    const float* ln1_g   = (const float*)d_in[6];
    const float* ln1_b   = (const float*)d_in[7];
    const float* ln2_g   = (const float*)d_in[8];
    const float* ln2_b   = (const float*)d_in[9];
    const float* fc1_w   = (const float*)d_in[10];
    const float* fc1_b   = (const float*)d_in[11];
    const float* fc2_w   = (const float*)d_in[12];
    const float* fc2_b   = (const float*)d_in[13];
    const float* lnf_g   = (const float*)d_in[14];
    const float* lnf_b   = (const float*)d_in[15];
    float* out = (float*)d_out;

    // workspace layout (bytes):
    // x fp32 8MB | qkvbuf fp32 24MB | abuf1 bf16 4MB | abuf2 bf16 16MB | wbuf bf16 8.4MB
    char* w = (char*)d_ws;
    float*  x      = (float*)w;                          w += (size_t)MM_ * CC_ * 4;
    float*  qkvbuf = (float*)w;                          w += (size_t)MM_ * 3 * CC_ * 4;
    ushort* abuf1  = (ushort*)w;                         w += (size_t)MM_ * CC_ * 2;
    ushort* abuf2  = (ushort*)w;                         w += (size_t)MM_ * HID_ * 2;
    ushort* wbuf   = (ushort*)w;

    embed_kernel<<<MM_, 256, 0, stream>>>(idx, (const float4*)tok_emb,
                                          (const float4*)pos_emb, (float4*)x);
    for (int l = 0; l < LL_; ++l) {
        // h = LN1(x) -> bf16
        ln_kernel<<<MM_, 256, 0, stream>>>(x, ln1_g + l * CC_, ln1_b + l * CC_, abuf1);
        // qkv = h @ qkv_w (no bias), fp32 out
        convt_kernel<<<dim3(3 * CC_ / 64, CC_ / 64), 256, 0, stream>>>(
            qkv_w + (size_t)l * CC_ * 3 * CC_, wbuf, CC_, 3 * CC_);
        mgemm<0, false, false, false, false><<<dim3(MM_ / 128, 3 * CC_ / 128), 256, 0, stream>>>(
            abuf1, wbuf, nullptr, nullptr, qkvbuf, MM_, 3 * CC_, CC_);
        // att -> bf16
        attn_kernel<<<dim3(TB_, BB_ * HH_), 64, 0, stream>>>(qkvbuf, abuf1);
        // x = x + att @ proj_w + proj_b
        convt_kernel<<<dim3(CC_ / 64, CC_ / 64), 256, 0, stream>>>(
            proj_w + (size_t)l * CC_ * CC_, wbuf, CC_, CC_);
        mgemm<0, true, false, true, false><<<dim3(MM_ / 128, CC_ / 128), 256, 0, stream>>>(
            abuf1, wbuf, proj_b + l * CC_, x, x, MM_, CC_, CC_);
        // h = LN2(x) -> bf16
        ln_kernel<<<MM_, 256, 0, stream>>>(x, ln2_g + l * CC_, ln2_b + l * CC_, abuf1);
        // hid = gelu(h @ fc1_w + fc1_b) -> bf16
        convt_kernel<<<dim3(HID_ / 64, CC_ / 64), 256, 0, stream>>>(
            fc1_w + (size_t)l * CC_ * HID_, wbuf, CC_, HID_);
        mgemm<0, true, true, false, true><<<dim3(MM_ / 128, HID_ / 128), 256, 0, stream>>>(
            abuf1, wbuf, fc1_b + l * HID_, nullptr, abuf2, MM_, HID_, CC_);
        // x = x + hid @ fc2_w + fc2_b
        convt_kernel<<<dim3(CC_ / 64, HID_ / 64), 256, 0, stream>>>(
            fc2_w + (size_t)l * HID_ * CC_, wbuf, HID_, CC_);
        mgemm<0, true, false, true, false><<<dim3(MM_ / 128, CC_ / 128), 256, 0, stream>>>(
            abuf2, wbuf, fc2_b + l * CC_, x, x, MM_, CC_, HID_);
    }
    // final LN + tied lm_head (tok_emb fp32 [V,C] = B^T layout, reg-staged)
    ln_kernel<<<MM_, 256, 0, stream>>>(x, lnf_g, lnf_b, abuf1);
    mgemm<1, false, false, false, false><<<dim3(MM_ / 128, VV_ / 128), 256, 0, stream>>>(
        abuf1, tok_emb, nullptr, nullptr, out, MM_, VV_, CC_);
}